// Round 12
// baseline (201.285 us; speedup 1.0000x reference)
//
#include <hip/hip_runtime.h>

#define INV_N (1.0f / 4096.0f)

__device__ __forceinline__ void bf(float& ar, float& ai, float& br, float& bi,
                                   float s, float cs) {
    float tr = cs * br - s * bi;
    float ti = cs * bi + s * br;
    br = ar - tr; bi = ai - ti;
    ar = ar + tr; ai = ai + ti;
}

// Twiddle: angle = -2pi*(k/4096)*wk radians => rev = -(k/4096)*wk revolutions.
__device__ __forceinline__ void tw(int k, float wk, float* s, float* cs) {
    float rev = (float)k * (-INV_N) * wk;
    rev = __builtin_amdgcn_fractf(rev);          // [0,1), handles negatives
    *s  = __builtin_amdgcn_sinf(rev);            // sin(2*pi*rev)
    *cs = __builtin_amdgcn_cosf(rev);            // cos(2*pi*rev)
}

// Zero-VGPR w staging: global -> LDS direct. Doesn't consume destination
// registers, so the w convoy can't be serialized by the register allocator
// (R0-R10 lesson: VGPR=48 vs 32-reg ar/ai live set forced load-wait-compute
// chunking of any register-destined prefetch).
__device__ __forceinline__ void load_lds4(const float* gp, float* lp) {
    __builtin_amdgcn_global_load_lds(
        (const __attribute__((address_space(1))) void*)gp,
        (__attribute__((address_space(3))) void*)lp, 4, 0, 0);
}

// Raw barrier with LDS-only drain (vmcnt queue rides through; R10 win).
#define BAR() do { asm volatile("s_waitcnt lgkmcnt(0)" ::: "memory"); \
                   __builtin_amdgcn_s_barrier(); } while (0)

// Full-drain barrier for the staging handoff. R11 ERRATum: a counted
// vmcnt(16) here assumed exact VMEM emission order [staging..., data...];
// any compiler-inserted VMEM (scratch spill, interleave) silently breaks the
// count -> unretired staging -> garbage twiddles (absmax 265). vmcnt(0) is
// order-independent and therefore correct unconditionally.
#define STAGE_BAR() do { asm volatile("s_waitcnt vmcnt(0)" ::: "memory"); \
                         __builtin_amdgcn_s_barrier(); } while (0)

// Two-round 16 KB ownership exchange: consecutive-16 rows -> stride-4 rows.
// Parity predicate (pb + (m>>2) + (m&3)) & 1: what a thread flushes in a
// round is exactly what it refills in that round (no extra live VGPRs).
__device__ __forceinline__ void exchange(float2* tile, float (&ar)[16],
                                         float (&ai)[16], int pb, int c) {
#pragma unroll
    for (int par = 0; par < 2; ++par) {
#pragma unroll
        for (int m = 0; m < 16; ++m) {
            if (((pb + (m >> 2) + (m & 3)) & 1) == par) {
                int srow = (pb << 3) + (((m >> 2) << 1) | ((m & 3) >> 1));
                tile[srow * 64 + c] = make_float2(ar[m], ai[m]);
            }
        }
        BAR();
#pragma unroll
        for (int m = 0; m < 16; ++m) {
            if (((pb + (m >> 2) + (m & 3)) & 1) == par) {
                int srow = ((m >> 2) << 3) + ((m & 3) << 1) + (pb >> 1);
                float2 v = tile[srow * 64 + c];
                ar[m] = v.x; ai[m] = v.y;
            }
        }
        if (par == 0) BAR();
    }
}

// fft_lo w-slot map (55 rows):
//   [0,32):  row = 64*i          (phase-2 step-64 twiddles, slot pb+4m)
//   [32,48): row = (i-32)*128    (phase-2 step-32,          slot 32+pb+4i)
//   [48,55): row = (i-47)*256    (phase-1 s1[j],            slot 47+j)
__device__ __forceinline__ unsigned lo_row(int i) {
    if (i < 32) return (unsigned)(64 * i);
    if (i < 48) return (unsigned)((i - 32) * 128);
    return (unsigned)((i - 47) * 256);
}

// fft_hi w-slot map (63 rows):
//   [0,32):  row = rres + 64*i           (step-4096, slot pb+4m)
//   [32,48): row = (rres + 64*(i-32))*2  (step-2048, slot 32+pb+4i)
//   [48,56): row = (rres + 64*(i-48))*4  (h=8,  slot 48+r)
//   [56,60): row = (rres + 64*(i-56))*8  (h=4,  slot 56+r)
//   [60,62): row = (rres + 64*(i-60))*16 (h=2,  slot 60+r)
//   62:      row = rres*32               (h=1)
__device__ __forceinline__ unsigned hi_row(int i, int rres) {
    if (i < 32) return (unsigned)(rres + 64 * i);
    if (i < 48) return (unsigned)((rres + 64 * (i - 32)) * 2);
    if (i < 56) return (unsigned)((rres + 64 * (i - 48)) * 4);
    if (i < 60) return (unsigned)((rres + 64 * (i - 56)) * 8);
    if (i < 62) return (unsigned)((rres + 64 * (i - 60)) * 16);
    return (unsigned)(rres * 32);
}

// Kernel A: stages step=2..64. w staged to LDS (zero VGPR, deduped across
// waves: 55 rows/block vs 76 register-loads), data in registers.
__global__ __launch_bounds__(256) void fft_lo(const float* __restrict__ x,
                                              const float* __restrict__ w,
                                              float2* __restrict__ dst2,
                                              unsigned dst_lim2) {
    __shared__ __align__(16) float2 tile[32 * 64];   // 16 KB exchange
    __shared__ __align__(16) float  lds_w[55 * 64];  // 13.75 KB w stage
    const int t   = threadIdx.x;
    const int c   = t & 63;
    const int pb  = t >> 6;
    const int wv  = t >> 6;                          // wave id (64-thr waves)
    const int c0  = (blockIdx.x & 63) << 6;
    const int r0  = (blockIdx.x >> 6) << 6;
    const int src_r0 = r0 ^ 2048;      // initial permutation: new[i] = old[i^2048]
    const unsigned col = (unsigned)(c0 + c);

    // ---- 1) stage ALL w rows to LDS (zero VGPR, all in flight) ----
#pragma unroll
    for (int ii = 0; ii < 14; ++ii) {
        int i = 4 * ii + wv;                         // wave-uniform
        if (i < 55)
            load_lds4(w + (size_t)lo_row(i) * 4096u + col, lds_w + i * 64);
    }

    // ---- 2) data loads: rows 16*pb+m, imag = 0 (x read once -> nt) ----
    float ar[16], ai[16];
#pragma unroll
    for (int m = 0; m < 16; ++m) {
        unsigned gi = (unsigned)(src_r0 + 16 * pb + m) * 4096u + col;
        ar[m] = __builtin_nontemporal_load(&x[gi]);
        ai[m] = 0.f;
    }

    // ---- 3) full drain + barrier (order-independent; see STAGE_BAR note) ----
    STAGE_BAR();

    // ---- phase-1 twiddles from LDS (s1[0] = identity) ----
    float s1[8], c1[8];
    s1[0] = 0.f; c1[0] = 1.f;
#pragma unroll
    for (int j = 1; j < 8; ++j)
        tw(256 * j, lds_w[(47 + j) * 64 + c], &s1[j], &c1[j]);

    // ---- phase 1: h = 1,2,4,8 (steps 2..16); twiddle index = r*8/h ----
#pragma unroll
    for (int h = 1; h <= 8; h <<= 1) {
        const int step = h << 1;
#pragma unroll
        for (int r = 0; r < h; ++r) {
            const int ti = r * (8 / h);
            const float s = s1[ti], cs = c1[ti];
#pragma unroll
            for (int b = 0; b < 8 / h; ++b) {
                const int mt = b * step + r;
                bf(ar[mt], ai[mt], ar[mt + h], ai[mt + h], s, cs);
            }
        }
    }

    // ---- ownership exchange (raw barriers) ----
    exchange(tile, ar, ai, pb, c);

    // ---- phase-2 twiddles from LDS, then butterflies ----
    float s2a[4], c2a[4], s2b[8], c2b[8];
#pragma unroll
    for (int i = 0; i < 4; ++i)
        tw((pb + 4 * i) * 128, lds_w[(32 + pb + 4 * i) * 64 + c], &s2a[i], &c2a[i]);
#pragma unroll
    for (int i = 0; i < 8; ++i)
        tw((pb + 4 * i) * 64, lds_w[(pb + 4 * i) * 64 + c], &s2b[i], &c2b[i]);

#pragma unroll
    for (int rm = 0; rm < 4; ++rm) {
#pragma unroll
        for (int b = 0; b < 2; ++b) {
            const int mt = b * 8 + rm;
            bf(ar[mt], ai[mt], ar[mt + 4], ai[mt + 4], s2a[rm], c2a[rm]);
        }
    }
#pragma unroll
    for (int m = 0; m < 8; ++m)
        bf(ar[m], ai[m], ar[m + 8], ai[m + 8], s2b[m], c2b[m]);

    // ---- direct stores: rows r0 + pb + 4*m ----
#pragma unroll
    for (int m = 0; m < 16; ++m) {
        unsigned gi = (unsigned)(r0 + pb + 4 * m) * 4096u + col;
        if (gi < dst_lim2) dst2[gi] = make_float2(ar[m], ai[m]);
    }
}

// Kernel B: stages step=128..4096 on rows {rres + 64*j}. Same staging scheme
// (63 rows/block vs 108 register-loads in R10).
template <int REAL_OUT>
__global__ __launch_bounds__(256) void fft_hi(const float* __restrict__ w,
                                              const float2* __restrict__ src2,
                                              float2* __restrict__ dstc,
                                              float* __restrict__ dstr,
                                              unsigned dst_lim) {
    __shared__ __align__(16) float2 tile[32 * 64];   // 16 KB exchange
    __shared__ __align__(16) float  lds_w[63 * 64];  // 15.75 KB w stage
    const int t    = threadIdx.x;
    const int c    = t & 63;
    const int pb   = t >> 6;
    const int wv   = t >> 6;
    const int rres = blockIdx.x >> 6;
    const unsigned col = (unsigned)(((blockIdx.x & 63) << 6) + c);

    // ---- 1) stage ALL w rows to LDS ----
#pragma unroll
    for (int ii = 0; ii < 16; ++ii) {
        int i = 4 * ii + wv;                         // wave-uniform
        if (i < 63)
            load_lds4(w + (size_t)hi_row(i, rres) * 4096u + col, lds_w + i * 64);
    }

    // ---- 2) data loads: global rows rres + 64*(16*pb+m) ----
    float ar[16], ai[16];
#pragma unroll
    for (int m = 0; m < 16; ++m) {
        unsigned gi = (unsigned)(rres + 64 * (16 * pb + m)) * 4096u + col;
        float2 v = src2[gi];
        ar[m] = v.x; ai[m] = v.y;
    }

    // ---- 3) full drain + barrier ----
    STAGE_BAR();

    // ---- phase 1: global steps 128, 256, 512, 1024 (w from LDS) ----
    {
        float s, cs;
        tw(rres * 32, lds_w[62 * 64 + c], &s, &cs);
#pragma unroll
        for (int b = 0; b < 8; ++b)
            bf(ar[2 * b], ai[2 * b], ar[2 * b + 1], ai[2 * b + 1], s, cs);
    }
#pragma unroll
    for (int r = 0; r < 2; ++r) {
        float s, cs;
        tw((rres + 64 * r) * 16, lds_w[(60 + r) * 64 + c], &s, &cs);
#pragma unroll
        for (int b = 0; b < 4; ++b) {
            const int mt = b * 4 + r;
            bf(ar[mt], ai[mt], ar[mt + 2], ai[mt + 2], s, cs);
        }
    }
#pragma unroll
    for (int r = 0; r < 4; ++r) {
        float s, cs;
        tw((rres + 64 * r) * 8, lds_w[(56 + r) * 64 + c], &s, &cs);
#pragma unroll
        for (int b = 0; b < 2; ++b) {
            const int mt = b * 8 + r;
            bf(ar[mt], ai[mt], ar[mt + 4], ai[mt + 4], s, cs);
        }
    }
#pragma unroll
    for (int r = 0; r < 8; ++r) {
        float s, cs;
        tw((rres + 64 * r) * 4, lds_w[(48 + r) * 64 + c], &s, &cs);
        bf(ar[r], ai[r], ar[r + 8], ai[r + 8], s, cs);
    }

    // ---- ownership exchange (raw barriers) ----
    exchange(tile, ar, ai, pb, c);

    // ---- phase-2 twiddles from LDS, then butterflies ----
    float s2a[4], c2a[4], s2b[8], c2b[8];
#pragma unroll
    for (int i = 0; i < 4; ++i)
        tw((rres + 64 * (pb + 4 * i)) * 2, lds_w[(32 + pb + 4 * i) * 64 + c],
           &s2a[i], &c2a[i]);
#pragma unroll
    for (int i = 0; i < 8; ++i)
        tw(rres + 64 * (pb + 4 * i), lds_w[(pb + 4 * i) * 64 + c],
           &s2b[i], &c2b[i]);

#pragma unroll
    for (int rm = 0; rm < 4; ++rm) {
#pragma unroll
        for (int b = 0; b < 2; ++b) {
            const int mt = b * 8 + rm;
            bf(ar[mt], ai[mt], ar[mt + 4], ai[mt + 4], s2a[rm], c2a[rm]);
        }
    }
#pragma unroll
    for (int m = 0; m < 8; ++m)
        bf(ar[m], ai[m], ar[m + 8], ai[m + 8], s2b[m], c2b[m]);

    // ---- stores: rows rres + 64*(pb+4*m), row-major output ----
    if (REAL_OUT) {
#pragma unroll
        for (int m = 0; m < 16; ++m) {
            unsigned gi = (unsigned)(rres + 64 * (pb + 4 * m)) * 4096u + col;
            if (gi < dst_lim) __builtin_nontemporal_store(ar[m], &dstr[gi]);
        }
    } else {
#pragma unroll
        for (int m = 0; m < 16; ++m) {
            unsigned gi = (unsigned)(rres + 64 * (pb + 4 * m)) * 4096u + col;
            if (gi < dst_lim) dstc[gi] = make_float2(ar[m], ai[m]);
        }
    }
}

extern "C" void kernel_launch(void* const* d_in, const int* in_sizes, int n_in,
                              void* d_out, int out_size, void* d_ws, size_t ws_size,
                              hipStream_t stream) {
    const float* x = (const float*)d_in[0];
    const float* w = (const float*)d_in[1];
    const long long NN = 4096LL * 4096LL;

    if ((long long)out_size >= 2 * NN) {
        // d_out = interleaved complex (2*N*N floats): compute in-place.
        float2* o2 = (float2*)d_out;
        unsigned lim2 = (unsigned)(out_size / 2);          // float2 units
        fft_lo<<<4096, 256, 0, stream>>>(x, w, o2, lim2);
        fft_hi<0><<<4096, 256, 0, stream>>>(w, o2, o2, nullptr, lim2);
    } else {
        // Confirmed world: d_out = N*N floats (real part). Complex
        // intermediate in d_ws (>= 2*N*N floats, verified earlier rounds).
        float2* ws2 = (float2*)d_ws;
        unsigned ws_lim2 = (unsigned)(ws_size / 8);        // bytes -> float2 units
        unsigned out_lim = (unsigned)out_size;             // float units
        fft_lo<<<4096, 256, 0, stream>>>(x, w, ws2, ws_lim2);
        fft_hi<1><<<4096, 256, 0, stream>>>(w, (const float2*)ws2, nullptr,
                                            (float*)d_out, out_lim);
    }
}